// Round 1
// baseline (325.027 us; speedup 1.0000x reference)
//
#include <hip/hip_runtime.h>

#define B_ROWS   16384
#define K_NB     64
#define D_DIM    256
#define TWO_D    512
#define R_BLK    8          // rows per block
#define THREADS  256

__global__ __launch_bounds__(THREADS)
void easyrec_fused(const int* __restrict__ nodes_u,
                   const int* __restrict__ nodes_v,
                   const int* __restrict__ neighbors,
                   const int* __restrict__ neighbor_counts,
                   const float* __restrict__ u2e,
                   const float* __restrict__ v2e,
                   const float* __restrict__ W,      // [D, 2D] row-major
                   const float* __restrict__ bias,   // [D]
                   float* __restrict__ out)          // [B]
{
    __shared__ int   nbr_lds[R_BLK * K_NB];                 // 2 KB
    __shared__ __align__(16) float cat_lds[R_BLK][TWO_D];   // 16 KB: [self | nmean]
    __shared__ float red_lds[R_BLK * 4];
    __shared__ float selfdot_lds[R_BLK];
    __shared__ float bdot_lds[R_BLK];

    const int t    = threadIdx.x;
    const int wave = t >> 6;
    const int lane = t & 63;
    const int row0 = blockIdx.x * R_BLK;

    // ---- stage neighbor indices for the 8 rows (512 ints, coalesced) ----
    nbr_lds[t]           = neighbors[(size_t)row0 * K_NB + t];
    nbr_lds[t + THREADS] = neighbors[(size_t)row0 * K_NB + t + THREADS];
    __syncthreads();

    // ---- phase 1: gather + mean-pool. wave w owns rows w and w+4; lane l owns cols 4l..4l+3 ----
    for (int rr = 0; rr < 2; ++rr) {
        const int r   = wave + rr * 4;
        const int row = row0 + r;
        const int nu  = __builtin_amdgcn_readfirstlane(nodes_u[row]);
        const int nv  = __builtin_amdgcn_readfirstlane(nodes_v[row]);
        const int cnt = __builtin_amdgcn_readfirstlane(neighbor_counts[row]);

        const float4 self4 = *(const float4*)(u2e + (size_t)nu * D_DIM + 4 * lane);
        const float4 v4    = *(const float4*)(v2e + (size_t)nv * D_DIM + 4 * lane);
        const float4 b4    = *(const float4*)(bias + 4 * lane);

        float4 acc = make_float4(0.f, 0.f, 0.f, 0.f);
        for (int k = 0; k < cnt; ++k) {
            const int idx = nbr_lds[r * K_NB + k];          // wave-uniform broadcast read
            const float4 nb4 = *(const float4*)(u2e + (size_t)idx * D_DIM + 4 * lane);
            acc.x += nb4.x; acc.y += nb4.y; acc.z += nb4.z; acc.w += nb4.w;
        }
        const float inv = 1.0f / (float)(cnt > 0 ? cnt : 1);
        float4 nm = make_float4(acc.x * inv, acc.y * inv, acc.z * inv, acc.w * inv);

        *(float4*)(&cat_lds[r][4 * lane])         = self4;
        *(float4*)(&cat_lds[r][D_DIM + 4 * lane]) = nm;

        // per-row scalars: self·v (cnt==0 fallback) and b·v (bias term)
        float sv = self4.x * v4.x + self4.y * v4.y + self4.z * v4.z + self4.w * v4.w;
        float bv = b4.x * v4.x + b4.y * v4.y + b4.z * v4.z + b4.w * v4.w;
        #pragma unroll
        for (int off = 32; off > 0; off >>= 1) {
            sv += __shfl_xor(sv, off, 64);
            bv += __shfl_xor(bv, off, 64);
        }
        if (lane == 0) { selfdot_lds[r] = sv; bdot_lds[r] = bv; }
    }
    __syncthreads();

    // ---- phase 2: t_j = sum_d W[d, j] * v[d]; thread t owns j = 2t, 2t+1 for all 8 rows ----
    // v rows read with uniform (readfirstlane) addresses -> scalar-load path, broadcast free.
    const float* vrow[R_BLK];
    #pragma unroll
    for (int r = 0; r < R_BLK; ++r) {
        const int nv = __builtin_amdgcn_readfirstlane(nodes_v[row0 + r]);
        vrow[r] = v2e + (size_t)nv * D_DIM;
    }

    float2 acc2[R_BLK];
    #pragma unroll
    for (int r = 0; r < R_BLK; ++r) acc2[r] = make_float2(0.f, 0.f);

    for (int d = 0; d < D_DIM; d += 4) {
        float4 vq[R_BLK];
        #pragma unroll
        for (int r = 0; r < R_BLK; ++r) vq[r] = *(const float4*)(vrow[r] + d);

        #pragma unroll
        for (int dd = 0; dd < 4; ++dd) {
            const float2 wq = *(const float2*)(W + (size_t)(d + dd) * TWO_D + 2 * t);
            #pragma unroll
            for (int r = 0; r < R_BLK; ++r) {
                const float vs = (dd == 0) ? vq[r].x : (dd == 1) ? vq[r].y
                               : (dd == 2) ? vq[r].z : vq[r].w;
                acc2[r].x += wq.x * vs;
                acc2[r].y += wq.y * vs;
            }
        }
    }

    // ---- epilogue: score = sum_j cat[j] * t_j  (+ b·v), reduce across block ----
    #pragma unroll
    for (int r = 0; r < R_BLK; ++r) {
        const float2 c2 = *(const float2*)(&cat_lds[r][2 * t]);
        float p = c2.x * acc2[r].x + c2.y * acc2[r].y;
        #pragma unroll
        for (int off = 32; off > 0; off >>= 1) p += __shfl_xor(p, off, 64);
        if (lane == 0) red_lds[r * 4 + wave] = p;
    }
    __syncthreads();

    if (t < R_BLK) {
        const int row = row0 + t;
        const int cnt = neighbor_counts[row];
        float s;
        if (cnt > 0) {
            s = red_lds[t * 4 + 0] + red_lds[t * 4 + 1]
              + red_lds[t * 4 + 2] + red_lds[t * 4 + 3] + bdot_lds[t];
        } else {
            s = selfdot_lds[t];
        }
        out[row] = s;
    }
}

extern "C" void kernel_launch(void* const* d_in, const int* in_sizes, int n_in,
                              void* d_out, int out_size, void* d_ws, size_t ws_size,
                              hipStream_t stream) {
    const int*   nodes_u         = (const int*)d_in[0];
    const int*   nodes_v         = (const int*)d_in[1];
    const int*   neighbors       = (const int*)d_in[2];
    const int*   neighbor_counts = (const int*)d_in[3];
    const float* u2e             = (const float*)d_in[4];
    const float* v2e             = (const float*)d_in[5];
    const float* W               = (const float*)d_in[6];
    const float* bias            = (const float*)d_in[7];
    float*       out             = (float*)d_out;

    const int blocks = B_ROWS / R_BLK;   // 2048
    easyrec_fused<<<blocks, THREADS, 0, stream>>>(
        nodes_u, nodes_v, neighbors, neighbor_counts, u2e, v2e, W, bias, out);
}

// Round 2
// 316.339 us; speedup vs baseline: 1.0275x; 1.0275x over previous
//
#include <hip/hip_runtime.h>

#define B_ROWS   16384
#define K_NB     64
#define D_DIM    256
#define TWO_D    512
#define R_BLK    8          // rows per block
#define THREADS  256

__global__ __launch_bounds__(THREADS)
void easyrec_fused(const int* __restrict__ nodes_u,
                   const int* __restrict__ nodes_v,
                   const int* __restrict__ neighbors,
                   const int* __restrict__ neighbor_counts,
                   const float* __restrict__ u2e,
                   const float* __restrict__ v2e,
                   const float* __restrict__ W,      // [D, 2D] row-major
                   const float* __restrict__ bias,   // [D]
                   float* __restrict__ out)          // [B]
{
    __shared__ __align__(16) int nbr_lds[R_BLK * K_NB];     // 2 KB
    __shared__ __align__(16) float cat_lds[R_BLK][TWO_D];   // 16 KB: [self | nmean]
    __shared__ float red_lds[R_BLK * 4];
    __shared__ float selfdot_lds[R_BLK];
    __shared__ float bdot_lds[R_BLK];

    const int t    = threadIdx.x;
    const int wave = t >> 6;
    const int lane = t & 63;
    const int row0 = blockIdx.x * R_BLK;

    // ---- stage neighbor indices for the 8 rows (512 ints, coalesced) ----
    nbr_lds[t]           = neighbors[(size_t)row0 * K_NB + t];
    nbr_lds[t + THREADS] = neighbors[(size_t)row0 * K_NB + t + THREADS];
    __syncthreads();

    // ---- phase 1: gather + mean-pool. wave w owns rows w and w+4; lane l owns cols 4l..4l+3 ----
    // 8-wide unroll: 8 independent float4 loads in flight per iteration (latency-bound fix).
    // neighbors[] entries are always valid indices, so over-reading past cnt is safe; the
    // tail chunk masks the accumulate instead of running a serial remainder loop.
    for (int rr = 0; rr < 2; ++rr) {
        const int r   = wave + rr * 4;
        const int row = row0 + r;
        const int nu  = __builtin_amdgcn_readfirstlane(nodes_u[row]);
        const int nv  = __builtin_amdgcn_readfirstlane(nodes_v[row]);
        const int cnt = __builtin_amdgcn_readfirstlane(neighbor_counts[row]);

        const float4 self4 = *(const float4*)(u2e + (size_t)nu * D_DIM + 4 * lane);
        const float4 v4    = *(const float4*)(v2e + (size_t)nv * D_DIM + 4 * lane);
        const float4 b4    = *(const float4*)(bias + 4 * lane);

        float4 acc = make_float4(0.f, 0.f, 0.f, 0.f);
        const int base = r * K_NB;
        const int kmax = (cnt + 7) & ~7;
        for (int k = 0; k < kmax; k += 8) {
            const int4 ia = *(const int4*)&nbr_lds[base + k];
            const int4 ib = *(const int4*)&nbr_lds[base + k + 4];
            const float4 n0 = *(const float4*)(u2e + (size_t)ia.x * D_DIM + 4 * lane);
            const float4 n1 = *(const float4*)(u2e + (size_t)ia.y * D_DIM + 4 * lane);
            const float4 n2 = *(const float4*)(u2e + (size_t)ia.z * D_DIM + 4 * lane);
            const float4 n3 = *(const float4*)(u2e + (size_t)ia.w * D_DIM + 4 * lane);
            const float4 n4 = *(const float4*)(u2e + (size_t)ib.x * D_DIM + 4 * lane);
            const float4 n5 = *(const float4*)(u2e + (size_t)ib.y * D_DIM + 4 * lane);
            const float4 n6 = *(const float4*)(u2e + (size_t)ib.z * D_DIM + 4 * lane);
            const float4 n7 = *(const float4*)(u2e + (size_t)ib.w * D_DIM + 4 * lane);
            if (k + 8 <= cnt) {
                acc.x += n0.x + n1.x + n2.x + n3.x + n4.x + n5.x + n6.x + n7.x;
                acc.y += n0.y + n1.y + n2.y + n3.y + n4.y + n5.y + n6.y + n7.y;
                acc.z += n0.z + n1.z + n2.z + n3.z + n4.z + n5.z + n6.z + n7.z;
                acc.w += n0.w + n1.w + n2.w + n3.w + n4.w + n5.w + n6.w + n7.w;
            } else {
                const float m0 = (k + 0 < cnt) ? 1.f : 0.f;
                const float m1 = (k + 1 < cnt) ? 1.f : 0.f;
                const float m2 = (k + 2 < cnt) ? 1.f : 0.f;
                const float m3 = (k + 3 < cnt) ? 1.f : 0.f;
                const float m4 = (k + 4 < cnt) ? 1.f : 0.f;
                const float m5 = (k + 5 < cnt) ? 1.f : 0.f;
                const float m6 = (k + 6 < cnt) ? 1.f : 0.f;
                const float m7 = (k + 7 < cnt) ? 1.f : 0.f;
                acc.x += n0.x*m0 + n1.x*m1 + n2.x*m2 + n3.x*m3 + n4.x*m4 + n5.x*m5 + n6.x*m6 + n7.x*m7;
                acc.y += n0.y*m0 + n1.y*m1 + n2.y*m2 + n3.y*m3 + n4.y*m4 + n5.y*m5 + n6.y*m6 + n7.y*m7;
                acc.z += n0.z*m0 + n1.z*m1 + n2.z*m2 + n3.z*m3 + n4.z*m4 + n5.z*m5 + n6.z*m6 + n7.z*m7;
                acc.w += n0.w*m0 + n1.w*m1 + n2.w*m2 + n3.w*m3 + n4.w*m4 + n5.w*m5 + n6.w*m6 + n7.w*m7;
            }
        }
        const float inv = 1.0f / (float)(cnt > 0 ? cnt : 1);
        float4 nm = make_float4(acc.x * inv, acc.y * inv, acc.z * inv, acc.w * inv);

        *(float4*)(&cat_lds[r][4 * lane])         = self4;
        *(float4*)(&cat_lds[r][D_DIM + 4 * lane]) = nm;

        // per-row scalars: self·v (cnt==0 fallback) and b·v (bias term)
        float sv = self4.x * v4.x + self4.y * v4.y + self4.z * v4.z + self4.w * v4.w;
        float bv = b4.x * v4.x + b4.y * v4.y + b4.z * v4.z + b4.w * v4.w;
        #pragma unroll
        for (int off = 32; off > 0; off >>= 1) {
            sv += __shfl_xor(sv, off, 64);
            bv += __shfl_xor(bv, off, 64);
        }
        if (lane == 0) { selfdot_lds[r] = sv; bdot_lds[r] = bv; }
    }
    __syncthreads();

    // ---- phase 2: t_j = sum_d W[d, j] * v[d]; thread t owns j = 2t, 2t+1 for all 8 rows ----
    const float* vrow[R_BLK];
    #pragma unroll
    for (int r = 0; r < R_BLK; ++r) {
        const int nv = __builtin_amdgcn_readfirstlane(nodes_v[row0 + r]);
        vrow[r] = v2e + (size_t)nv * D_DIM;
    }

    float2 acc2[R_BLK];
    #pragma unroll
    for (int r = 0; r < R_BLK; ++r) acc2[r] = make_float2(0.f, 0.f);

    for (int d = 0; d < D_DIM; d += 4) {
        float4 vq[R_BLK];
        #pragma unroll
        for (int r = 0; r < R_BLK; ++r) vq[r] = *(const float4*)(vrow[r] + d);

        #pragma unroll
        for (int dd = 0; dd < 4; ++dd) {
            const float2 wq = *(const float2*)(W + (size_t)(d + dd) * TWO_D + 2 * t);
            #pragma unroll
            for (int r = 0; r < R_BLK; ++r) {
                const float vs = (dd == 0) ? vq[r].x : (dd == 1) ? vq[r].y
                               : (dd == 2) ? vq[r].z : vq[r].w;
                acc2[r].x += wq.x * vs;
                acc2[r].y += wq.y * vs;
            }
        }
    }

    // ---- epilogue: score = sum_j cat[j] * t_j  (+ b·v), reduce across block ----
    #pragma unroll
    for (int r = 0; r < R_BLK; ++r) {
        const float2 c2 = *(const float2*)(&cat_lds[r][2 * t]);
        float p = c2.x * acc2[r].x + c2.y * acc2[r].y;
        #pragma unroll
        for (int off = 32; off > 0; off >>= 1) p += __shfl_xor(p, off, 64);
        if (lane == 0) red_lds[r * 4 + wave] = p;
    }
    __syncthreads();

    if (t < R_BLK) {
        const int row = row0 + t;
        const int cnt = neighbor_counts[row];
        float s;
        if (cnt > 0) {
            s = red_lds[t * 4 + 0] + red_lds[t * 4 + 1]
              + red_lds[t * 4 + 2] + red_lds[t * 4 + 3] + bdot_lds[t];
        } else {
            s = selfdot_lds[t];
        }
        out[row] = s;
    }
}

extern "C" void kernel_launch(void* const* d_in, const int* in_sizes, int n_in,
                              void* d_out, int out_size, void* d_ws, size_t ws_size,
                              hipStream_t stream) {
    const int*   nodes_u         = (const int*)d_in[0];
    const int*   nodes_v         = (const int*)d_in[1];
    const int*   neighbors       = (const int*)d_in[2];
    const int*   neighbor_counts = (const int*)d_in[3];
    const float* u2e             = (const float*)d_in[4];
    const float* v2e             = (const float*)d_in[5];
    const float* W               = (const float*)d_in[6];
    const float* bias            = (const float*)d_in[7];
    float*       out             = (float*)d_out;

    const int blocks = B_ROWS / R_BLK;   // 2048
    easyrec_fused<<<blocks, THREADS, 0, stream>>>(
        nodes_u, nodes_v, neighbors, neighbor_counts, u2e, v2e, W, bias, out);
}